// Round 3
// baseline (493.813 us; speedup 1.0000x reference)
//
#include <hip/hip_runtime.h>
#include <hip/hip_fp16.h>

#define IN_DIM 29
#define XDIM 32
#define OUT_DIM 64
#define BN_EPS 1e-5f

#define BW      128      // dsts per bucket (LDS tile: 128*64*4 = 32 KB)
#define BW_LOG  7
#define NBLK    128      // partition blocks -> ~16-edge (64 B) runs per (block,bucket)
#define MAXBUCK 1024     // static LDS arrays; n_nodes <= 131072 ok
#define SENT    INT_MIN

// ===========================================================================
// out[d][o] = max_{src in N(d)} yq[src][o] + (beta - a*mean - a*(W[:,29:32].node_d))[o]
// yq[n][o] = a[o] * (W[o,:] . [feat_n; node_n]),  a = gamma/rsqrt(var+eps)
// Empty segment -> 0.
// ===========================================================================

// --- K1: per-node transform -> fp16 table yq[n][64] ------------------------
__global__ __launch_bounds__(256) void node_transform_kernel(
    const float* __restrict__ features, const float* __restrict__ node,
    const float* __restrict__ weight, const float* __restrict__ gamma,
    const float* __restrict__ rvar,
    __half* __restrict__ yq, int n_nodes, int npw)
{
    const int lane = threadIdx.x & 63;
    const int wave = (blockIdx.x * blockDim.x + threadIdx.x) >> 6;
    int n0 = wave * npw;
    int n1 = n0 + npw; if (n1 > n_nodes) n1 = n_nodes;

    float w[XDIM];
    const float4* wp = (const float4*)(weight + lane * XDIM);
#pragma unroll
    for (int q = 0; q < 8; ++q) {
        float4 v = wp[q];
        w[4*q+0] = v.x; w[4*q+1] = v.y; w[4*q+2] = v.z; w[4*q+3] = v.w;
    }
    const float a = gamma[lane] * __frsqrt_rn(rvar[lane] + BN_EPS);

    for (int n = n0; n < n1; ++n) {
        const float* f = features + (size_t)n * IN_DIM;
        float acc = 0.0f;
#pragma unroll
        for (int i = 0; i < IN_DIM; ++i) acc = fmaf(f[i], w[i], acc);
        const float* nd = node + (size_t)n * 3;
#pragma unroll
        for (int j = 0; j < 3; ++j) acc = fmaf(nd[j], w[IN_DIM + j], acc);
        yq[(size_t)n * OUT_DIM + lane] = __float2half(acc * a);
    }
}

// --- K2: per-block bucket histogram (LDS atomics only) ---------------------
__global__ __launch_bounds__(256) void count_kernel(
    const int* __restrict__ edges, int* __restrict__ gHist,
    int n_edges, int nbuck, int chunk)
{
    __shared__ int h[MAXBUCK];
    for (int i = threadIdx.x; i < nbuck; i += 256) h[i] = 0;
    __syncthreads();
    const int e0 = blockIdx.x * chunk;
    const int e1 = min(e0 + chunk, n_edges);
    for (int e = e0 + threadIdx.x; e < e1; e += 256)
        atomicAdd(&h[edges[2*e] >> BW_LOG], 1);
    __syncthreads();
    for (int i = threadIdx.x; i < nbuck; i += 256)
        gHist[i * NBLK + blockIdx.x] = h[i];
}

// --- scan over nbuck*NBLK (bucket-major) -----------------------------------
__global__ __launch_bounds__(256) void scan_a_kernel(
    const int* __restrict__ counts, int n,
    int* __restrict__ excl, int* __restrict__ aux)
{
    const int t = threadIdx.x;
    const int base = blockIdx.x * 1024 + t * 4;
    int v[4];
#pragma unroll
    for (int k = 0; k < 4; ++k) v[k] = (base + k < n) ? counts[base + k] : 0;
    int tsum = v[0] + v[1] + v[2] + v[3];

    const int lane = t & 63, wv = t >> 6;
    int x = tsum;
#pragma unroll
    for (int off = 1; off < 64; off <<= 1) {
        int y = __shfl_up(x, off);
        if (lane >= off) x += y;
    }
    __shared__ int wsum[4];
    if (lane == 63) wsum[wv] = x;
    __syncthreads();
    int wexcl = 0;
    for (int i = 0; i < wv; ++i) wexcl += wsum[i];
    int run = wexcl + x - tsum;
#pragma unroll
    for (int k = 0; k < 4; ++k) {
        if (base + k < n) excl[base + k] = run;
        run += v[k];
    }
    if (t == 255) aux[blockIdx.x] = run;
}

__global__ void scan_b_kernel(int* __restrict__ aux, int nb) {
    if (threadIdx.x == 0 && blockIdx.x == 0) {
        int run = 0;
        for (int i = 0; i < nb; ++i) { int t = aux[i]; aux[i] = run; run += t; }
    }
}

__global__ void scan_c_kernel(int* __restrict__ offsets, const int* __restrict__ aux,
                              int n) {
    int t = blockIdx.x * blockDim.x + threadIdx.x;
    if (t < n) offsets[t] += aux[t >> 10];
}

// --- K4: multisplit partition. LDS cursors -> contiguous per-(block,bucket)
//         runs of ~16 x 4 B keys; no global atomics. ------------------------
__global__ __launch_bounds__(256) void partition_kernel(
    const int* __restrict__ edges, const int* __restrict__ gOffs,
    int* __restrict__ keys, int n_edges, int nbuck, int chunk)
{
    __shared__ int cur[MAXBUCK];
    for (int i = threadIdx.x; i < nbuck; i += 256)
        cur[i] = gOffs[i * NBLK + blockIdx.x];
    __syncthreads();
    const int e0 = blockIdx.x * chunk;
    const int e1 = min(e0 + chunk, n_edges);
    for (int e = e0 + threadIdx.x; e < e1; e += 256) {
        const int dst = edges[2*e], src = edges[2*e+1];
        const int b = dst >> BW_LOG;
        const int pos = atomicAdd(&cur[b], 1);
        keys[pos] = (dst & (BW - 1)) | (src << BW_LOG);
    }
}

// --- K5: fused pool. One WG per bucket of 128 dsts; segment-max via LDS
//         ds_max atomics; epilogue fuses BN const + dst node term + write. --
__global__ __launch_bounds__(256) void pool_fused_kernel(
    const int* __restrict__ gOffs, const int* __restrict__ keys,
    const __half* __restrict__ yq, const float* __restrict__ node,
    const float* __restrict__ weight, const float* __restrict__ gamma,
    const float* __restrict__ beta, const float* __restrict__ rmean,
    const float* __restrict__ rvar,
    float* __restrict__ out, int n_nodes, int n_edges, int nbuck)
{
    __shared__ int acc[BW * OUT_DIM];   // 32 KB
    const int tid = threadIdx.x;
    const int lane = tid & 63, wid = tid >> 6;
    const int b = blockIdx.x;

    {   // init to sentinel, vectorized
        int4* p = (int4*)acc;
        for (int i = tid; i < BW * OUT_DIM / 4; i += 256)
            p[i] = make_int4(SENT, SENT, SENT, SENT);
    }
    __syncthreads();

    const int beg = gOffs[b * NBLK];
    const int end = (b == nbuck - 1) ? n_edges : gOffs[(b + 1) * NBLK];

    // wave-uniform edge loop, 8-deep MLP on the 128 B yq gathers
    for (int j = beg + wid * 8; j < end; j += 32) {
#pragma unroll
        for (int u = 0; u < 8; ++u) {
            const int e = j + u;
            if (e < end) {
                const int key = keys[e];
                const int src = key >> BW_LOG;
                const int dlo = key & (BW - 1);
                const float v = __half2float(yq[(size_t)src * OUT_DIM + lane]);
                int iv = __float_as_int(v);
                iv = (iv < 0) ? (iv ^ 0x7FFFFFFF) : iv;
                atomicMax(&acc[dlo * OUT_DIM + lane], iv);   // ds_max, no return
            }
        }
    }
    __syncthreads();

    const float a  = gamma[lane] * __frsqrt_rn(rvar[lane] + BN_EPS);
    const float bp = beta[lane] - rmean[lane] * a;
    const float w29 = weight[lane * XDIM + 29] * a;
    const float w30 = weight[lane * XDIM + 30] * a;
    const float w31 = weight[lane * XDIM + 31] * a;

    for (int d = wid; d < BW; d += 4) {
        const int dg = b * BW + d;
        if (dg >= n_nodes) break;
        const int k = acc[d * OUT_DIM + lane];
        float r;
        if (k == SENT) {
            r = 0.0f;
        } else {
            const int ib = (k < 0) ? (k ^ 0x7FFFFFFF) : k;
            const float nx = node[(size_t)dg * 3 + 0];
            const float ny = node[(size_t)dg * 3 + 1];
            const float nz = node[(size_t)dg * 3 + 2];
            r = __int_as_float(ib) + (bp - (w29 * nx + w30 * ny + w31 * nz));
        }
        out[(size_t)dg * OUT_DIM + lane] = r;
    }
}

// ===========================================================================
// Fallback path (workspace too small): round-1 direct atomic kernels
// ===========================================================================
__global__ void init_kernel(int4* __restrict__ out, int total4) {
    int t = blockIdx.x * blockDim.x + threadIdx.x;
    if (t < total4) out[t] = make_int4(SENT, SENT, SENT, SENT);
}

__global__ __launch_bounds__(256) void edge_atomic_kernel(
    const int* __restrict__ edges,
    const float* __restrict__ features, const float* __restrict__ node,
    const float* __restrict__ weight, const float* __restrict__ gamma,
    const float* __restrict__ beta, const float* __restrict__ rmean,
    const float* __restrict__ rvar,
    int* __restrict__ out, int n_edges, int epw)
{
    const int lane = threadIdx.x & 63;
    const int wave = (blockIdx.x * blockDim.x + threadIdx.x) >> 6;
    int e0 = wave * epw, e1 = e0 + epw;
    if (e1 > n_edges) e1 = n_edges;

    float w[XDIM];
    const float4* wp = (const float4*)(weight + lane * XDIM);
#pragma unroll
    for (int q = 0; q < 8; ++q) {
        float4 v = wp[q];
        w[4*q+0] = v.x; w[4*q+1] = v.y; w[4*q+2] = v.z; w[4*q+3] = v.w;
    }
    const float a = gamma[lane] * __frsqrt_rn(rvar[lane] + BN_EPS);
    const float bprime = beta[lane] - rmean[lane] * a;

    for (int e = e0; e < e1; ++e) {
        const int dst = edges[2*e+0], src = edges[2*e+1];
        float x[XDIM];
#pragma unroll
        for (int i = 0; i < IN_DIM; ++i) x[i] = features[(size_t)src * IN_DIM + i];
#pragma unroll
        for (int j = 0; j < 3; ++j)
            x[IN_DIM+j] = node[(size_t)src*3+j] - node[(size_t)dst*3+j];
        float acc = 0.0f;
#pragma unroll
        for (int i = 0; i < XDIM; ++i) acc = fmaf(x[i], w[i], acc);
        float msg = fmaf(acc, a, bprime);
        int bb = __float_as_int(msg);
        int key = (bb < 0) ? (bb ^ 0x7FFFFFFF) : bb;
        atomicMax(out + (size_t)dst * OUT_DIM + lane, key);
    }
}

__global__ void decode_kernel(int* __restrict__ out, int total) {
    int t = blockIdx.x * blockDim.x + threadIdx.x;
    if (t >= total) return;
    int k = out[t];
    float r;
    if (k == SENT) r = 0.0f;
    else { int b = (k < 0) ? (k ^ 0x7FFFFFFF) : k; r = __int_as_float(b); }
    ((float*)out)[t] = r;
}

// ===========================================================================
extern "C" void kernel_launch(void* const* d_in, const int* in_sizes, int n_in,
                              void* d_out, int out_size, void* d_ws, size_t ws_size,
                              hipStream_t stream) {
    const float* node     = (const float*)d_in[0];
    const float* features = (const float*)d_in[1];
    const int*   edges    = (const int*)d_in[2];
    const float* weight   = (const float*)d_in[3];
    const float* gamma    = (const float*)d_in[4];
    const float* beta     = (const float*)d_in[5];
    const float* rmean    = (const float*)d_in[6];
    const float* rvar     = (const float*)d_in[7];

    const int n_nodes = in_sizes[0] / 3;
    const int n_edges = in_sizes[2] / 2;

    const int nbuck = (n_nodes + BW - 1) >> BW_LOG;       // 782
    const int n_scan = nbuck * NBLK;                      // ~100k
    const int nb_scan = (n_scan + 1023) / 1024;
    const int chunk = (n_edges + NBLK - 1) / NBLK;

    // workspace layout
    size_t off = 0;
    auto alloc = [&](size_t bytes) { size_t r = off; off = (off + bytes + 15) & ~(size_t)15; return r; };
    size_t o_yq   = alloc((size_t)n_nodes * OUT_DIM * sizeof(__half));
    size_t o_hist = alloc((size_t)n_scan * sizeof(int));
    size_t o_offs = alloc((size_t)n_scan * sizeof(int));
    size_t o_aux  = alloc((size_t)nb_scan * sizeof(int));
    size_t o_keys = alloc((size_t)n_edges * sizeof(int));
    const size_t need = off;

    const int n_waves = 8192;
    const int npw = (n_nodes + n_waves - 1) / n_waves;

    if (ws_size >= need && nbuck <= MAXBUCK && n_nodes < (1 << (31 - BW_LOG))) {
        char* base  = (char*)d_ws;
        __half* yq  = (__half*)(base + o_yq);
        int* gHist  = (int*)(base + o_hist);
        int* gOffs  = (int*)(base + o_offs);
        int* aux    = (int*)(base + o_aux);
        int* keys   = (int*)(base + o_keys);

        node_transform_kernel<<<n_waves / 4, 256, 0, stream>>>(
            features, node, weight, gamma, rvar, yq, n_nodes, npw);
        count_kernel<<<NBLK, 256, 0, stream>>>(edges, gHist, n_edges, nbuck, chunk);
        scan_a_kernel<<<nb_scan, 256, 0, stream>>>(gHist, n_scan, gOffs, aux);
        scan_b_kernel<<<1, 64, 0, stream>>>(aux, nb_scan);
        scan_c_kernel<<<(n_scan + 255) / 256, 256, 0, stream>>>(gOffs, aux, n_scan);
        partition_kernel<<<NBLK, 256, 0, stream>>>(edges, gOffs, keys, n_edges, nbuck, chunk);
        pool_fused_kernel<<<nbuck, 256, 0, stream>>>(
            gOffs, keys, yq, node, weight, gamma, beta, rmean, rvar,
            (float*)d_out, n_nodes, n_edges, nbuck);
    } else {
        int* out_i = (int*)d_out;
        const int total4 = out_size / 4;
        init_kernel<<<(total4 + 255) / 256, 256, 0, stream>>>((int4*)out_i, total4);
        const int epw = (n_edges + n_waves - 1) / n_waves;
        edge_atomic_kernel<<<n_waves / 4, 256, 0, stream>>>(
            edges, features, node, weight, gamma, beta, rmean, rvar,
            out_i, n_edges, epw);
        decode_kernel<<<(out_size + 255) / 256, 256, 0, stream>>>(out_i, out_size);
    }
}

// Round 4
// 254.499 us; speedup vs baseline: 1.9403x; 1.9403x over previous
//
#include <hip/hip_runtime.h>
#include <hip/hip_fp16.h>

#define IN_DIM 29
#define XDIM 32
#define OUT_DIM 64
#define BN_EPS 1e-5f

#define BW      64       // dsts per bucket (LDS tile: 64*64*4 = 16 KB)
#define BW_LOG  6
#define NBLK    256      // count/partition blocks (multisplit granularity)
#define GROUP   16       // edges per branchless pool group
#define MAXBUCK 2048     // static LDS arrays; n_nodes <= 131072
#define SENT    0        // ordered-u16 sentinel: any real enc > 0

// ===========================================================================
// out[d][o] = max_{src in N(d)} y[src][o] + (beta - a*mean - a*(W[:,29:32].node_d))[o]
// y[n][o] = a[o] * (W[o,:] . [feat_n; node_n]),  a = gamma*rsqrt(var+eps)
// y stored as monotone ordered-u16 fp16 encoding; empty segment -> 0.
// ===========================================================================

// --- K1: per-node transform -> ordered-u16 table yq[n][64] -----------------
__global__ __launch_bounds__(256) void node_transform_kernel(
    const float* __restrict__ features, const float* __restrict__ node,
    const float* __restrict__ weight, const float* __restrict__ gamma,
    const float* __restrict__ rvar,
    unsigned short* __restrict__ yq, int n_nodes, int npw)
{
    const int lane = threadIdx.x & 63;
    const int wave = (blockIdx.x * blockDim.x + threadIdx.x) >> 6;
    int n0 = wave * npw;
    int n1 = n0 + npw; if (n1 > n_nodes) n1 = n_nodes;

    float w[XDIM];
    const float4* wp = (const float4*)(weight + lane * XDIM);
#pragma unroll
    for (int q = 0; q < 8; ++q) {
        float4 v = wp[q];
        w[4*q+0] = v.x; w[4*q+1] = v.y; w[4*q+2] = v.z; w[4*q+3] = v.w;
    }
    const float a = gamma[lane] * __frsqrt_rn(rvar[lane] + BN_EPS);

    for (int n = n0; n < n1; ++n) {
        const float* f = features + (size_t)n * IN_DIM;
        float acc = 0.0f;
#pragma unroll
        for (int i = 0; i < IN_DIM; ++i) acc = fmaf(f[i], w[i], acc);
        const float* nd = node + (size_t)n * 3;
#pragma unroll
        for (int j = 0; j < 3; ++j) acc = fmaf(nd[j], w[IN_DIM + j], acc);
        unsigned short h = __half_as_ushort(__float2half(acc * a));
        unsigned short enc = (h & 0x8000) ? (unsigned short)(~h)
                                          : (unsigned short)(h | 0x8000);
        yq[(size_t)n * OUT_DIM + lane] = enc;
    }
}

// --- K2: per-block bucket histogram (LDS atomics only) ---------------------
__global__ __launch_bounds__(256) void count_kernel(
    const int* __restrict__ edges, int* __restrict__ gHist,
    int n_edges, int nbuck, int chunk)
{
    __shared__ int h[MAXBUCK];
    for (int i = threadIdx.x; i < nbuck; i += 256) h[i] = 0;
    __syncthreads();
    const int e0 = blockIdx.x * chunk;
    const int e1 = min(e0 + chunk, n_edges);
    for (int e = e0 + threadIdx.x; e < e1; e += 256)
        atomicAdd(&h[edges[2*e] >> BW_LOG], 1);
    __syncthreads();
    for (int i = threadIdx.x; i < nbuck; i += 256)
        gHist[i * NBLK + blockIdx.x] = h[i];
}

// --- scan over nbuck*NBLK (bucket-major) -----------------------------------
__global__ __launch_bounds__(256) void scan_a_kernel(
    const int* __restrict__ counts, int n,
    int* __restrict__ excl, int* __restrict__ aux)
{
    const int t = threadIdx.x;
    const int base = blockIdx.x * 1024 + t * 4;
    int v[4];
#pragma unroll
    for (int k = 0; k < 4; ++k) v[k] = (base + k < n) ? counts[base + k] : 0;
    int tsum = v[0] + v[1] + v[2] + v[3];

    const int lane = t & 63, wv = t >> 6;
    int x = tsum;
#pragma unroll
    for (int off = 1; off < 64; off <<= 1) {
        int y = __shfl_up(x, off);
        if (lane >= off) x += y;
    }
    __shared__ int wsum[4];
    if (lane == 63) wsum[wv] = x;
    __syncthreads();
    int wexcl = 0;
    for (int i = 0; i < wv; ++i) wexcl += wsum[i];
    int run = wexcl + x - tsum;
#pragma unroll
    for (int k = 0; k < 4; ++k) {
        if (base + k < n) excl[base + k] = run;
        run += v[k];
    }
    if (t == 255) aux[blockIdx.x] = run;
}

// single-block parallel scan of aux (nb up to a few thousand)
__global__ __launch_bounds__(256) void scan_b_kernel(int* __restrict__ aux, int nb) {
    const int t = threadIdx.x;
    const int lane = t & 63, wv = t >> 6;
    __shared__ int wsum[4];
    __shared__ int s_run;
    if (t == 0) s_run = 0;
    __syncthreads();
    for (int base = 0; base < nb; base += 256) {
        const int i = base + t;
        int v = (i < nb) ? aux[i] : 0;
        int x = v;
#pragma unroll
        for (int off = 1; off < 64; off <<= 1) {
            int y = __shfl_up(x, off);
            if (lane >= off) x += y;
        }
        if (lane == 63) wsum[wv] = x;
        __syncthreads();
        int wexcl = 0;
        for (int k = 0; k < wv; ++k) wexcl += wsum[k];
        const int run = s_run;
        if (i < nb) aux[i] = run + wexcl + x - v;   // exclusive
        __syncthreads();
        if (t == 255) s_run = run + wexcl + x;      // running total
        __syncthreads();
    }
}

__global__ void scan_c_kernel(int* __restrict__ offsets, const int* __restrict__ aux,
                              int n) {
    int t = blockIdx.x * blockDim.x + threadIdx.x;
    if (t < n) offsets[t] += aux[t >> 10];
}

// --- K4: multisplit partition -> per-bucket contiguous key runs ------------
__global__ __launch_bounds__(256) void partition_kernel(
    const int* __restrict__ edges, const int* __restrict__ gOffs,
    int* __restrict__ keys, int n_edges, int nbuck, int chunk)
{
    __shared__ int cur[MAXBUCK];
    for (int i = threadIdx.x; i < nbuck; i += 256)
        cur[i] = gOffs[i * NBLK + blockIdx.x];
    __syncthreads();
    const int e0 = blockIdx.x * chunk;
    const int e1 = min(e0 + chunk, n_edges);
    for (int e = e0 + threadIdx.x; e < e1; e += 256) {
        const int dst = edges[2*e], src = edges[2*e+1];
        const int b = dst >> BW_LOG;
        const int pos = atomicAdd(&cur[b], 1);
        keys[pos] = (dst & (BW - 1)) | (src << BW_LOG);
    }
}

// --- K5: fused pool. One WG per bucket of 64 dsts; ordered-u16 ds_max; -----
//         epilogue decodes + fuses BN const + dst node term + coalesced write.
__global__ __launch_bounds__(256) void pool_fused_kernel(
    const int* __restrict__ gOffs, const int* __restrict__ keys,
    const unsigned short* __restrict__ yq, const float* __restrict__ node,
    const float* __restrict__ weight, const float* __restrict__ gamma,
    const float* __restrict__ beta, const float* __restrict__ rmean,
    const float* __restrict__ rvar,
    float* __restrict__ out, int n_nodes, int n_edges, int nbuck)
{
    __shared__ int acc[BW * OUT_DIM];   // 16 KB
    const int tid = threadIdx.x;
    const int lane = tid & 63, wid = tid >> 6;
    const int b = blockIdx.x;

    {   // init to sentinel 0
        int4* p = (int4*)acc;
        for (int i = tid; i < BW * OUT_DIM / 4; i += 256)
            p[i] = make_int4(SENT, SENT, SENT, SENT);
    }
    __syncthreads();

    const int beg = gOffs[b * NBLK];
    const int end = (b == nbuck - 1) ? n_edges : gOffs[(b + 1) * NBLK];
    const int cnt = end - beg;
    const int slice = (cnt + 3) >> 2;          // per-wave contiguous slice
    const int w_beg = beg + wid * slice;
    const int w_end = min(w_beg + slice, end);

    int j = w_beg;
    // branchless 16-deep groups: 1 lane-strided load = 16 keys, then readlane
    for (; j + GROUP <= w_end; j += GROUP) {
        const int kv = keys[j + (lane & (GROUP - 1))];
#pragma unroll
        for (int u = 0; u < GROUP; ++u) {
            const int key = __builtin_amdgcn_readlane(kv, u);
            const int src = key >> BW_LOG;
            const int dlo = key & (BW - 1);
            const unsigned int v = yq[(size_t)src * OUT_DIM + lane];
            atomicMax(&acc[dlo * OUT_DIM + lane], (int)v);
        }
    }
    for (; j < w_end; ++j) {                   // tail (< GROUP edges)
        const int key = keys[j];
        const int src = key >> BW_LOG;
        const int dlo = key & (BW - 1);
        const unsigned int v = yq[(size_t)src * OUT_DIM + lane];
        atomicMax(&acc[dlo * OUT_DIM + lane], (int)v);
    }
    __syncthreads();

    const float a  = gamma[lane] * __frsqrt_rn(rvar[lane] + BN_EPS);
    const float bp = beta[lane] - rmean[lane] * a;
    const float w29 = weight[lane * XDIM + 29] * a;
    const float w30 = weight[lane * XDIM + 30] * a;
    const float w31 = weight[lane * XDIM + 31] * a;

    for (int d = wid; d < BW; d += 4) {
        const int dg = b * BW + d;
        if (dg >= n_nodes) break;
        const int k = acc[d * OUT_DIM + lane];
        float r;
        if (k == SENT) {
            r = 0.0f;
        } else {
            const unsigned short enc = (unsigned short)k;
            const unsigned short h = (enc & 0x8000) ? (unsigned short)(enc ^ 0x8000)
                                                    : (unsigned short)(~enc);
            const float v = __half2float(__ushort_as_half(h));
            const float nx = node[(size_t)dg * 3 + 0];
            const float ny = node[(size_t)dg * 3 + 1];
            const float nz = node[(size_t)dg * 3 + 2];
            r = v + (bp - (w29 * nx + w30 * ny + w31 * nz));
        }
        out[(size_t)dg * OUT_DIM + lane] = r;
    }
}

// ===========================================================================
// Fallback path (workspace too small): round-1 direct atomic kernels
// ===========================================================================
__global__ void init_kernel(int4* __restrict__ out, int total4) {
    int t = blockIdx.x * blockDim.x + threadIdx.x;
    if (t < total4) out[t] = make_int4(INT_MIN, INT_MIN, INT_MIN, INT_MIN);
}

__global__ __launch_bounds__(256) void edge_atomic_kernel(
    const int* __restrict__ edges,
    const float* __restrict__ features, const float* __restrict__ node,
    const float* __restrict__ weight, const float* __restrict__ gamma,
    const float* __restrict__ beta, const float* __restrict__ rmean,
    const float* __restrict__ rvar,
    int* __restrict__ out, int n_edges, int epw)
{
    const int lane = threadIdx.x & 63;
    const int wave = (blockIdx.x * blockDim.x + threadIdx.x) >> 6;
    int e0 = wave * epw, e1 = e0 + epw;
    if (e1 > n_edges) e1 = n_edges;

    float w[XDIM];
    const float4* wp = (const float4*)(weight + lane * XDIM);
#pragma unroll
    for (int q = 0; q < 8; ++q) {
        float4 v = wp[q];
        w[4*q+0] = v.x; w[4*q+1] = v.y; w[4*q+2] = v.z; w[4*q+3] = v.w;
    }
    const float a = gamma[lane] * __frsqrt_rn(rvar[lane] + BN_EPS);
    const float bprime = beta[lane] - rmean[lane] * a;

    for (int e = e0; e < e1; ++e) {
        const int dst = edges[2*e+0], src = edges[2*e+1];
        float x[XDIM];
#pragma unroll
        for (int i = 0; i < IN_DIM; ++i) x[i] = features[(size_t)src * IN_DIM + i];
#pragma unroll
        for (int j = 0; j < 3; ++j)
            x[IN_DIM+j] = node[(size_t)src*3+j] - node[(size_t)dst*3+j];
        float acc = 0.0f;
#pragma unroll
        for (int i = 0; i < XDIM; ++i) acc = fmaf(x[i], w[i], acc);
        float msg = fmaf(acc, a, bprime);
        int bb = __float_as_int(msg);
        int key = (bb < 0) ? (bb ^ 0x7FFFFFFF) : bb;
        atomicMax(out + (size_t)dst * OUT_DIM + lane, key);
    }
}

__global__ void decode_kernel(int* __restrict__ out, int total) {
    int t = blockIdx.x * blockDim.x + threadIdx.x;
    if (t >= total) return;
    int k = out[t];
    float r;
    if (k == INT_MIN) r = 0.0f;
    else { int b = (k < 0) ? (k ^ 0x7FFFFFFF) : k; r = __int_as_float(b); }
    ((float*)out)[t] = r;
}

// ===========================================================================
extern "C" void kernel_launch(void* const* d_in, const int* in_sizes, int n_in,
                              void* d_out, int out_size, void* d_ws, size_t ws_size,
                              hipStream_t stream) {
    const float* node     = (const float*)d_in[0];
    const float* features = (const float*)d_in[1];
    const int*   edges    = (const int*)d_in[2];
    const float* weight   = (const float*)d_in[3];
    const float* gamma    = (const float*)d_in[4];
    const float* beta     = (const float*)d_in[5];
    const float* rmean    = (const float*)d_in[6];
    const float* rvar     = (const float*)d_in[7];

    const int n_nodes = in_sizes[0] / 3;
    const int n_edges = in_sizes[2] / 2;

    const int nbuck = (n_nodes + BW - 1) >> BW_LOG;       // 1563
    const int n_scan = nbuck * NBLK;                      // ~400k
    const int nb_scan = (n_scan + 1023) / 1024;
    const int chunk = (n_edges + NBLK - 1) / NBLK;

    // workspace layout
    size_t off = 0;
    auto alloc = [&](size_t bytes) { size_t r = off; off = (off + bytes + 15) & ~(size_t)15; return r; };
    size_t o_yq   = alloc((size_t)n_nodes * OUT_DIM * sizeof(unsigned short));
    size_t o_hist = alloc((size_t)n_scan * sizeof(int));
    size_t o_offs = alloc((size_t)n_scan * sizeof(int));
    size_t o_aux  = alloc((size_t)nb_scan * sizeof(int));
    size_t o_keys = alloc((size_t)n_edges * sizeof(int));
    const size_t need = off;

    const int n_waves = 8192;
    const int npw = (n_nodes + n_waves - 1) / n_waves;

    if (ws_size >= need && nbuck <= MAXBUCK && n_nodes <= MAXBUCK * BW) {
        char* base  = (char*)d_ws;
        unsigned short* yq = (unsigned short*)(base + o_yq);
        int* gHist  = (int*)(base + o_hist);
        int* gOffs  = (int*)(base + o_offs);
        int* aux    = (int*)(base + o_aux);
        int* keys   = (int*)(base + o_keys);

        node_transform_kernel<<<n_waves / 4, 256, 0, stream>>>(
            features, node, weight, gamma, rvar, yq, n_nodes, npw);
        count_kernel<<<NBLK, 256, 0, stream>>>(edges, gHist, n_edges, nbuck, chunk);
        scan_a_kernel<<<nb_scan, 256, 0, stream>>>(gHist, n_scan, gOffs, aux);
        scan_b_kernel<<<1, 256, 0, stream>>>(aux, nb_scan);
        scan_c_kernel<<<(n_scan + 255) / 256, 256, 0, stream>>>(gOffs, aux, n_scan);
        partition_kernel<<<NBLK, 256, 0, stream>>>(edges, gOffs, keys, n_edges, nbuck, chunk);
        pool_fused_kernel<<<nbuck, 256, 0, stream>>>(
            gOffs, keys, yq, node, weight, gamma, beta, rmean, rvar,
            (float*)d_out, n_nodes, n_edges, nbuck);
    } else {
        int* out_i = (int*)d_out;
        const int total4 = out_size / 4;
        init_kernel<<<(total4 + 255) / 256, 256, 0, stream>>>((int4*)out_i, total4);
        const int epw = (n_edges + n_waves - 1) / n_waves;
        edge_atomic_kernel<<<n_waves / 4, 256, 0, stream>>>(
            edges, features, node, weight, gamma, beta, rmean, rvar,
            out_i, n_edges, epw);
        decode_kernel<<<(out_size + 255) / 256, 256, 0, stream>>>(out_i, out_size);
    }
}